// Round 5
// baseline (164.761 us; speedup 1.0000x reference)
//
#include <hip/hip_runtime.h>
#include <stdint.h>

typedef unsigned short u16;

#define NPIX     129600      // 270*480
#define NC       50          // candidates incl. input-mv
#define N2       49          // block-match candidates (7x7)
#define PXB      32          // pixels per block (32*800 floats = 256 thr * 25 float4)
#define NITER    25          // float4 loads per thread per input
// float32-element offsets into d_out (outputs concatenated in return order)
#define OUT_TMPL 259200
#define OUT_MASK 2332800
#define OUT_COST 2462400

// rank[flat] = position of flat index (j+3)*7+(i+3) in the center-out spiral.
// Verified by full step-by-step simulation of _spiral_order(3); produced the
// passing round-3 kernel (absmax 0).
__constant__ unsigned char RANKLUT[49] = {
  42,43,44,45,46,47,48,
  41,20,21,22,23,24,25,
  40,19, 6, 7, 8, 9,26,
  39,18, 5, 0, 1,10,27,
  38,17, 4, 3, 2,11,28,
  37,16,15,14,13,12,29,
  36,35,34,33,32,31,30
};

__global__ __launch_bounds__(256) void cv_kernel(
    const float* __restrict__ w1,
    const float* __restrict__ w2,
    float* __restrict__ out)
{
  __shared__ u16 lds_cost[PXB * NC];   // 3200 B

  const int tid  = threadIdx.x;
  const int lane = tid & 63;
  const int wv   = tid >> 6;
  const int P0   = blockIdx.x * PXB;          // block's first pixel
  const long B4  = (long)P0 * 200;            // float4 base of block's chunk

  const float4* w1v = (const float4*)w1;
  const float4* w2v = (const float4*)w2;

  // ---- phase 1: dense streaming SAD. Every lane of every load carries 16
  // useful bytes; addresses are block-contiguous -> perfect coalescing.
  // Candidate c_blk = F>>2 = lp*50 + cand occupies lanes 4k..4k+3 (4 | 256).
#pragma unroll 5
  for (int i = 0; i < NITER; ++i) {
    const int F = i * 256 + tid;              // flat float4 idx in block chunk
    float4 a = w1v[B4 + F];
    float4 b = w2v[B4 + F];
    float s = fabsf(a.x - b.x) + fabsf(a.y - b.y)
            + fabsf(a.z - b.z) + fabsf(a.w - b.w);
    s += __shfl_xor(s, 1, 64);
    s += __shfl_xor(s, 2, 64);
    if ((tid & 3) == 0) lds_cost[i * 64 + (tid >> 2)] = (u16)(int)s; // exact <=4080
  }
  __syncthreads();

  // ---- phase 2: per-pixel spiral-first argmin. Wave wv owns 8 pixels.
  for (int k = 0; k < PXB / 4; ++k) {         // 8 pixels per wave (FIXED: was /4/2)
    const int lp = wv * 8 + k;                // local pixel 0..31
    const int p  = P0 + lp;                   // global pixel

    const int cost = (lane < NC) ? (int)lds_cost[lp * NC + lane] : 0x7FFFF;
    // key = cost(12b) | spiral_rank(6b) | flat(6b) -> lexicographic argmin
    int key = (lane < N2) ? ((cost << 12) | ((int)RANKLUT[lane] << 6) | lane)
                          : 0x7FFFFFFF;
#pragma unroll
    for (int m = 32; m >= 1; m >>= 1) {
      int o = __shfl_xor(key, m, 64);
      key = min(key, o);
    }
    const int cost49   = (int)lds_cost[lp * NC + N2];  // LDS broadcast read
    const int flat_bm  = key & 63;
    const int cost_bm  = key >> 12;
    const bool mv      = cost49 < cost_bm;    // strict, per reference
    const int min_cost = mv ? cost49 : cost_bm;
    const int min_idx  = mv ? N2 : flat_bm;   // template index (may be 49)

    // min_templates: lanes 0..3 re-read the winning 64 B (L2-warm) and store
    if (lane < 4) {
      float4 t = w1v[(long)p * 200 + min_idx * 4 + lane];
      ((float4*)out)[OUT_TMPL / 4 + p * 4 + lane] = t;
    }
    if (lane == 0) {
      // vector = VEC_LUT[min_idx_bm] = (-j, -i); block-match index only
      const int jj = flat_bm / 7 - 3;
      const int ii = flat_bm % 7 - 3;
      *(float2*)(out + (long)p * 2) = make_float2((float)(-jj), (float)(-ii));
      out[OUT_MASK + p] = mv ? 1.0f : 0.0f;   // input_mv_mask
      out[OUT_COST + p] = (float)min_cost;    // min_cost_volume (exact in f32)
    }
  }
}

extern "C" void kernel_launch(void* const* d_in, const int* in_sizes, int n_in,
                              void* d_out, int out_size, void* d_ws, size_t ws_size,
                              hipStream_t stream) {
  const float* w1 = (const float*)d_in[0];
  const float* w2 = (const float*)d_in[1];
  float* out = (float*)d_out;
  dim3 grid(NPIX / PXB);   // 4050 blocks
  dim3 block(256);
  cv_kernel<<<grid, block, 0, stream>>>(w1, w2, out);
}

// Round 7
// 151.062 us; speedup vs baseline: 1.0907x; 1.0907x over previous
//
#include <hip/hip_runtime.h>
#include <stdint.h>

typedef unsigned short u16;
typedef float f4 __attribute__((ext_vector_type(4)));   // builtin vec for nontemporal

#define NPIX     129600      // 270*480
#define NC       50          // candidates incl. input-mv
#define N2       49          // block-match candidates (7x7)
#define PXB      32          // pixels per block (32*800 floats = 256 thr * 25 float4)
#define NITER    25          // float4 loads per thread per input
// float32-element offsets into d_out (outputs concatenated in return order)
#define OUT_TMPL 259200
#define OUT_MASK 2332800
#define OUT_COST 2462400

// rank[flat] = position of flat index (j+3)*7+(i+3) in the center-out spiral.
// Verified by full simulation of _spiral_order(3); two passing kernels used it.
__constant__ unsigned char RANKLUT[49] = {
  42,43,44,45,46,47,48,
  41,20,21,22,23,24,25,
  40,19, 6, 7, 8, 9,26,
  39,18, 5, 0, 1,10,27,
  38,17, 4, 3, 2,11,28,
  37,16,15,14,13,12,29,
  36,35,34,33,32,31,30
};

__global__ __launch_bounds__(256) void cv_kernel(
    const float* __restrict__ w1,
    const float* __restrict__ w2,
    float* __restrict__ out)
{
  // per-thread partials: lds_part[c_blk*4 + q], c_blk = lp*50+cand, q = elem quad
  __shared__ u16 lds_part[PXB * NC * 4];   // 6400 u16 = 12.8 KB

  const int tid  = threadIdx.x;
  const int lane = tid & 63;
  const int wv   = tid >> 6;
  const int P0   = blockIdx.x * PXB;          // block's first pixel
  const long B4  = (long)P0 * 200;            // float4 base of block's chunk

  const float4* w1v = (const float4*)w1;
  const f4*     w2v = (const f4*)w2;

  // ---- phase 1: dense streaming SAD, NO cross-lane ops in the hot loop.
  // Thread handles float4 F = i*256+tid; writes its 4-elem partial straight to
  // LDS (stride-1 ds_write_b16, 2 lanes/bank = conflict-free). w2 is read-once
  // -> nontemporal; w1 stays cached for the phase-2 template re-read.
#pragma unroll 5
  for (int i = 0; i < NITER; ++i) {
    const int F = i * 256 + tid;              // flat float4 idx in block chunk
    float4 a = w1v[B4 + F];
    f4 b = __builtin_nontemporal_load(&w2v[B4 + F]);
    float s = fabsf(a.x - b.x) + fabsf(a.y - b.y)
            + fabsf(a.z - b.z) + fabsf(a.w - b.w);
    lds_part[F] = (u16)(int)s;               // exact: partial <= 4*255 = 1020
  }
  __syncthreads();

  // ---- phase 2: per-pixel spiral-first argmin. Wave wv owns 8 pixels.
  for (int k = 0; k < 8; ++k) {               // 8 * 4 waves = 32 = PXB
    const int lp = wv * 8 + k;                // local pixel 0..31
    const int p  = P0 + lp;                   // global pixel

    int cost = 0;
    if (lane < NC) {                          // sum the 4 quad-partials (exact)
      const ushort4 pr = *(const ushort4*)&lds_part[(lp * NC + lane) * 4];
      cost = (int)pr.x + (int)pr.y + (int)pr.z + (int)pr.w;
    }
    const int cost49 = __shfl(cost, N2, 64);  // input-mv candidate cost
    // key = cost(12b) | spiral_rank(6b) | flat(6b) -> lexicographic argmin
    int key = (lane < N2) ? ((cost << 12) | ((int)RANKLUT[lane] << 6) | lane)
                          : 0x7FFFFFFF;
#pragma unroll
    for (int m = 32; m >= 1; m >>= 1) {
      int o = __shfl_xor(key, m, 64);
      key = min(key, o);
    }
    const int flat_bm  = key & 63;
    const int cost_bm  = key >> 12;
    const bool mv      = cost49 < cost_bm;    // strict, per reference
    const int min_cost = mv ? cost49 : cost_bm;
    const int min_idx  = mv ? N2 : flat_bm;   // template index (may be 49)

    // min_templates: lanes 0..3 re-read the winning 64 B (L2-warm) and store
    if (lane < 4) {
      float4 t = w1v[(long)p * 200 + min_idx * 4 + lane];
      ((float4*)out)[OUT_TMPL / 4 + p * 4 + lane] = t;
    }
    if (lane == 0) {
      // vector = VEC_LUT[min_idx_bm] = (-j, -i); block-match index only
      const int jj = flat_bm / 7 - 3;
      const int ii = flat_bm % 7 - 3;
      *(float2*)(out + (long)p * 2) = make_float2((float)(-jj), (float)(-ii));
      out[OUT_MASK + p] = mv ? 1.0f : 0.0f;   // input_mv_mask
      out[OUT_COST + p] = (float)min_cost;    // min_cost_volume (exact in f32)
    }
  }
}

extern "C" void kernel_launch(void* const* d_in, const int* in_sizes, int n_in,
                              void* d_out, int out_size, void* d_ws, size_t ws_size,
                              hipStream_t stream) {
  const float* w1 = (const float*)d_in[0];
  const float* w2 = (const float*)d_in[1];
  float* out = (float*)d_out;
  dim3 grid(NPIX / PXB);   // 4050 blocks
  dim3 block(256);
  cv_kernel<<<grid, block, 0, stream>>>(w1, w2, out);
}